// Round 11
// baseline (241.107 us; speedup 1.0000x reference)
//
#include <hip/hip_runtime.h>
#include <hip/hip_bf16.h>
#include <cstdint>

// B=2, HW=64 -> 128 rows of S=256; M = 32768. D=512, HEADS=8, DK=64,
// 3*H*DK=1536, KSIZE=7. Inputs/outputs fp32; internal compute bf16 MFMA.
//
// Round-11: DELETE the 96-MB X-conversion pass. The fused kernel reg-stages
// A directly from fp32 X (global->VGPR->cvt->ds_write) under its MFMA slack;
// prep shrinks to weights-only (~6 MB). Read pipeline (round 10) preserved:
// reads of tile t+1 issued before MFMA of tile t; all waits are vmcnt(0) /
// lgkmcnt(0) with >=1-body issue->wait distance.

typedef __bf16 bf16x8 __attribute__((ext_vector_type(8)));
typedef float f32x4 __attribute__((ext_vector_type(4)));
typedef uint32_t u32x4 __attribute__((ext_vector_type(4)));

__device__ __forceinline__ uint16_t f2bf(float f) {
    uint32_t u = __builtin_bit_cast(uint32_t, f);
    return (uint16_t)((u + 0x7fffu + ((u >> 16) & 1u)) >> 16);
}
__device__ __forceinline__ float bflo(uint32_t u) { return __builtin_bit_cast(float, u << 16); }
__device__ __forceinline__ float bfhi(uint32_t u) { return __builtin_bit_cast(float, u & 0xffff0000u); }

__device__ __forceinline__ void unpack8(uint4 v, float* f) {
    f[0] = bflo(v.x); f[1] = bfhi(v.x);
    f[2] = bflo(v.y); f[3] = bfhi(v.y);
    f[4] = bflo(v.z); f[5] = bfhi(v.z);
    f[6] = bflo(v.w); f[7] = bfhi(v.w);
}
__device__ __forceinline__ uint32_t pack2(float a, float b) {
    return (uint32_t)f2bf(a) | ((uint32_t)f2bf(b) << 16);
}

#define GLOAD_LDS16(gp, lp)                                                        \
    __builtin_amdgcn_global_load_lds((const __attribute__((address_space(1))) void*)(gp), \
                                     (__attribute__((address_space(3))) void*)(lp), 16, 0, 0)

// Inline-asm LDS / global ops: invisible to compiler waitcnt tracking; caller
// owns vmcnt/lgkmcnt discipline (wait + sched_barrier(0) before consumers).
__device__ __forceinline__ bf16x8 ds_read16(const uint16_t* p) {
    bf16x8 r;
    asm volatile("ds_read_b128 %0, %1"
                 : "=v"(r)
                 : "v"((const __attribute__((address_space(3))) void*)p));
    return r;
}
__device__ __forceinline__ void ds_write16(uint16_t* p, u32x4 w) {
    asm volatile("ds_write_b128 %0, %1"
                 :: "v"((__attribute__((address_space(3))) void*)p), "v"(w)
                 : "memory");
}
__device__ __forceinline__ f32x4 gload4f(const float* p) {
    f32x4 r;
    asm volatile("global_load_dwordx4 %0, %1, off"
                 : "=v"(r)
                 : "v"((const __attribute__((address_space(1))) void*)p));
    return r;
}

// ---------------------------------------------------------------------------
// prep: weight transposes ONLY (X conversion now fused). ~6 MB traffic.
// Wqkv: 512x1536 -> WqkvT 1536x512 bf16; Wout: 512x512 -> WoutT 512x512 bf16.
// ---------------------------------------------------------------------------
__global__ void prep(const float* __restrict__ Wqkv, const float* __restrict__ Wout,
                     uint16_t* __restrict__ WqkvT, uint16_t* __restrict__ WoutT) {
    int idx = blockIdx.x * 256 + threadIdx.x;
    if (idx < 512 * 1536) {
        int r = idx / 1536, c = idx - r * 1536;
        WqkvT[(size_t)c * 512 + r] = f2bf(Wqkv[idx]);
    } else {
        idx -= 512 * 1536;
        int r = idx >> 9, c = idx & 511;
        WoutT[(size_t)c * 512 + r] = f2bf(Wout[idx]);
    }
}

// ---------------------------------------------------------------------------
// FUSED qkv-projection + local-window attention; A reg-staged from fp32 X.
// Block = (bn, head): id = h*128 + bn (8 head-blocks of one bn -> same XCD).
// 512 threads = 8 waves (4 M x 2 N), wave tile 64x96, acc[4][6], BK=32, NT=16.
//
// LDS (uint16 elems): A bufs 2 x 8192 [0,16384); B bufs 2 x 6144
// [16384,28672). Attn union: Q [0,16384), K [16384,33152), V [33152,49920),
// P(f32) [49920,54016). Total 54016 elems = 105.5 KB, 1 block/CU.
//
// A-staging: thread (row = tid>>1, half = tid&1) loads 4 float4 (16 fp32) of
// X[bm0+row][t*32 + half*16 ..], packs to 16 bf16, writes 2 ds_write_b128 to
// the packed-2-rows XOR layout (chunk d = ln*8 + ((hr*4+c)^(ln&7))).
// B-staging: DMA from WqkvT bf16 (round-9 scheme, pre-swizzled source).
//
// Body t (all waits count-uniform; issue->wait distance >= 1 body):
//   vmcnt(0)        [stage(t+1): A-gl in regs + B-DMA landed; ~600cyc cover]
//   pack -> W_A(t+1) x2 ds_write -> Abuf[(t+1)&1]
//   lgkmcnt(0)      [drains R(t) (1-body-old; convoy-free) + W_A]
//   barrier         [publishes B(t+1)/W_A(t+1) landed for all waves]
//   R(t+1) x10      [from Abuf/Bbuf[(t+1)&1]]
//   stage(t+2): B-DMA -> Bbuf[t&1]; A-gl(t+2) -> regs
//   MFMA(t) x24 on fragset[t&1]   [covers R(t+1)+stage(t+2)]
// ---------------------------------------------------------------------------
__global__ __launch_bounds__(512, 2)
void gemm_qkv_attn(const float* __restrict__ X, const uint16_t* __restrict__ WqkvT,
                   const float* __restrict__ pb, uint16_t* __restrict__ attn) {
    __shared__ __align__(16) uint16_t lds[54016];  // 105.5 KB

    constexpr int KO = 16384;   // attn K array (elems)
    constexpr int VO = 33152;   // attn V array
    constexpr int PO = 49920;   // attn partial/p f32 buffer
    constexpr int BB = 16384;   // B-buf base (elems)

    const int tid  = threadIdx.x;
    const int lane = tid & 63;
    const int wv   = tid >> 6;
    const int r    = lane & 15;
    const int quad = lane >> 4;
    const int wr   = wv >> 1;   // 0..3  (M wave)
    const int wc   = wv & 1;    // 0..1  (N wave)
    const int h    = blockIdx.x >> 7;
    const int bn   = blockIdx.x & 127;
    const long bm0 = (long)bn * 256;

    // ---- A reg-staging constants: thread (row, half) ----
    const int arow_g = tid >> 1;          // 0..255
    const int ahalf  = tid & 1;
    const float* xsrc = X + (bm0 + arow_g) * 512L + ahalf * 16;
    const int a_ln = arow_g >> 1, a_hr = arow_g & 1;
    const int c0 = ahalf * 2, c1 = ahalf * 2 + 1;
    const int ad0 = (a_ln * 8 + ((a_hr * 4 + c0) ^ (a_ln & 7))) * 8;  // elem off
    const int ad1 = (a_ln * 8 + ((a_hr * 4 + c1) ^ (a_ln & 7))) * 8;

    // ---- B DMA staging constants (round-9 scheme, inverse swizzle on src) ----
#define SRC_ROWCOL(d_, row_, col_) do {                                                 \
        int ln_ = (d_) >> 3, pre_ = ((d_) & 7) ^ (ln_ & 7);                             \
        row_ = 2 * ln_ + (pre_ >> 2);                                                   \
        col_ = (pre_ & 3) * 8;                                                          \
    } while (0)
    int rB0, cB0, rB1, cB1;
    SRC_ROWCOL(tid,       rB0, cB0);           // B chunks 0..511
    SRC_ROWCOL(tid + 512, rB1, cB1);           // B chunks 512..767 (tid<256)
#undef SRC_ROWCOL
    const long gB0 = ((long)(rB0 >> 6)) * 512 + h * 64 + (rB0 & 63);
    const long gB1 = ((long)(rB1 >> 6)) * 512 + h * 64 + (rB1 & 63);
    const uint16_t* pB0 = WqkvT + gB0 * 512 + cB0;
    const uint16_t* pB1 = WqkvT + gB1 * 512 + cB1;

#define STAGE_B(qb_, t_) do {                                                           \
        GLOAD_LDS16(pB0 + (t_) * 32, &lds[BB + (qb_) * 6144 + tid * 8]);                \
        if (tid < 256)                                                                  \
            GLOAD_LDS16(pB1 + (t_) * 32, &lds[BB + (qb_) * 6144 + (tid + 512) * 8]);    \
    } while (0)

    f32x4 ag0, ag1, ag2, ag3;   // in-flight A fp32 (one tile)
#define A_GL(t_) do {                                                                   \
        const float* p_ = xsrc + (t_) * 32;                                             \
        ag0 = gload4f(p_);     ag1 = gload4f(p_ + 4);                                   \
        ag2 = gload4f(p_ + 8); ag3 = gload4f(p_ + 12);                                  \
    } while (0)

#define PACK_WRITE(x_) do {                                                             \
        u32x4 w0_, w1_;                                                                 \
        w0_[0] = pack2(ag0[0], ag0[1]); w0_[1] = pack2(ag0[2], ag0[3]);                 \
        w0_[2] = pack2(ag1[0], ag1[1]); w0_[3] = pack2(ag1[2], ag1[3]);                 \
        w1_[0] = pack2(ag2[0], ag2[1]); w1_[1] = pack2(ag2[2], ag2[3]);                 \
        w1_[2] = pack2(ag3[0], ag3[1]); w1_[3] = pack2(ag3[2], ag3[3]);                 \
        ds_write16(&lds[((x_) & 1) * 8192 + ad0], w0_);                                 \
        ds_write16(&lds[((x_) & 1) * 8192 + ad1], w1_);                                 \
    } while (0)

    // ---- compute-side lane constants (packed-2-rows XOR layout) ----
    const int p_ln  = (((r & 1) << 2) | quad) ^ ((r >> 1) & 7);
    const int aLane = wr * 2048 + (r >> 1) * 64 + p_ln * 8;        // + mf*512
    const int bLane = wc * 3072 + (r >> 1) * 64 + p_ln * 8;        // + nf*512

    f32x4 acc[4][6];
#pragma unroll
    for (int mf = 0; mf < 4; ++mf)
#pragma unroll
        for (int nf = 0; nf < 6; ++nf) acc[mf][nf] = (f32x4){0.f, 0.f, 0.f, 0.f};

    bf16x8 fA0[4], fB0[6], fA1[4], fB1[6];

#define READS(qb_, FA_, FB_) do {                                                       \
        const int ao_ = (qb_) * 8192, bo_ = BB + (qb_) * 6144;                          \
        _Pragma("unroll")                                                               \
        for (int nf_ = 0; nf_ < 6; ++nf_) FB_[nf_] = ds_read16(&lds[bo_ + bLane + nf_ * 512]); \
        _Pragma("unroll")                                                               \
        for (int mf_ = 0; mf_ < 4; ++mf_) FA_[mf_] = ds_read16(&lds[ao_ + aLane + mf_ * 512]); \
    } while (0)

#define BODY(T_, FAc_, FBc_, FAn_, FBn_) do {                                           \
        if ((T_) + 1 < 16) {                                                            \
            asm volatile("s_waitcnt vmcnt(0)" ::: "memory");                            \
            __builtin_amdgcn_sched_barrier(0);                                          \
            PACK_WRITE((T_) + 1);                                                       \
        }                                                                               \
        asm volatile("s_waitcnt lgkmcnt(0)" ::: "memory");                              \
        __builtin_amdgcn_sched_barrier(0);                                              \
        __builtin_amdgcn_s_barrier();                                                   \
        if ((T_) + 1 < 16) READS(((T_) + 1) & 1, FAn_, FBn_);                           \
        if ((T_) + 2 < 16) { STAGE_B((T_) & 1, (T_) + 2); A_GL((T_) + 2); }             \
        __builtin_amdgcn_sched_barrier(0);                                              \
        __builtin_amdgcn_s_setprio(1);                                                  \
        _Pragma("unroll")                                                               \
        for (int nf_ = 0; nf_ < 6; ++nf_)                                               \
            _Pragma("unroll")                                                           \
            for (int mf_ = 0; mf_ < 4; ++mf_)                                           \
                acc[mf_][nf_] = __builtin_amdgcn_mfma_f32_16x16x32_bf16(                \
                    FBc_[nf_], FAc_[mf_], acc[mf_][nf_], 0, 0, 0);                      \
        __builtin_amdgcn_s_setprio(0);                                                  \
    } while (0)

    // ---- prologue: stage(0), commit A(0); stage(1); read tile 0 ----
    STAGE_B(0, 0); A_GL(0);
    asm volatile("s_waitcnt vmcnt(0)" ::: "memory");
    __builtin_amdgcn_sched_barrier(0);
    PACK_WRITE(0);
    STAGE_B(1, 1); A_GL(1);
    asm volatile("s_waitcnt lgkmcnt(0)" ::: "memory");
    __builtin_amdgcn_s_barrier();
    READS(0, fA0, fB0);

    for (int tt = 0; tt < 16; tt += 2) {
        BODY(tt,     fA0, fB0, fA1, fB1);
        BODY(tt + 1, fA1, fB1, fA0, fB0);
    }

    // ---- all DMA/reads drained; barrier before overwriting LDS for attn ----
    asm volatile("s_waitcnt vmcnt(0) lgkmcnt(0)" ::: "memory");
    __builtin_amdgcn_s_barrier();

    // ---- zero-fill K/V halo rows (0,1,2,259,260,261) ----
    if (tid < 96) {
        int a    = tid / 48;
        int rem  = tid - a * 48;
        int hr6  = rem >> 3;
        int c8   = rem & 7;
        int hrow = (hr6 < 3) ? hr6 : (256 + hr6);
        ((uint4*)&lds[a ? VO : KO])[hrow * 8 + c8] = (uint4){0u, 0u, 0u, 0u};
    }

    // ---- spill acc (C^T frags: m = r, n = quad*4 + reg) -> attn layout ----
#pragma unroll
    for (int nf = 0; nf < 6; ++nf) {
        int arr, d0;
        if (wc == 0) { if (nf < 4) { arr = 0; d0 = nf * 16; } else { arr = 1; d0 = (nf - 4) * 16; } }
        else         { if (nf < 2) { arr = 1; d0 = 32 + nf * 16; } else { arr = 2; d0 = (nf - 2) * 16; } }
        const int base = (arr == 0) ? 0 : ((arr == 1) ? KO : VO);
        const int hofs = (arr == 0) ? 0 : 3;
        const int cc0  = (d0 >> 3) + (quad >> 1);
        const int sub  = (quad & 1) * 4;
#pragma unroll
        for (int mf = 0; mf < 4; ++mf) {
            int rowX = wr * 64 + mf * 16 + r + hofs;
            uint2 w;
            w.x = pack2(acc[mf][nf][0], acc[mf][nf][1]);
            w.y = pack2(acc[mf][nf][2], acc[mf][nf][3]);
            *(uint2*)&lds[base + rowX * 64 + ((cc0 ^ (rowX & 7)) << 3) + sub] = w;
        }
    }
    __syncthreads();

    // ================= attention phase =================
    const int s     = tid & 255;
    const int half  = tid >> 8;
    const int cbase = half * 4;
    float* pp = (float*)&lds[PO];   // [256][8] f32

    uint4 qc[4];
    const uint4* qarr = (const uint4*)lds;
#pragma unroll
    for (int c = 0; c < 4; ++c) qc[c] = qarr[s * 8 + ((cbase + c) ^ (s & 7))];

    float sc[7];
#pragma unroll
    for (int w = 0; w < 7; ++w) sc[w] = 0.f;
    const uint4* karr = (const uint4*)&lds[KO];
#pragma unroll
    for (int c = 0; c < 4; ++c) {
        float qf[8];
        unpack8(qc[c], qf);
#pragma unroll
        for (int w = 0; w < 7; ++w) {
            int hrow = s + w;
            uint4 kc = karr[hrow * 8 + ((cbase + c) ^ (hrow & 7))];
            float kf[8];
            unpack8(kc, kf);
#pragma unroll
            for (int j = 0; j < 8; ++j) sc[w] += qf[j] * kf[j];
        }
    }

    if (half == 1) {
#pragma unroll
        for (int w = 0; w < 7; ++w) pp[s * 8 + w] = sc[w];
    }
    __syncthreads();

    if (half == 0) {
        const float* pbr = pb + ((size_t)h * 256 + s) * 7;
        float mx = -1e30f, tot[7];
#pragma unroll
        for (int w = 0; w < 7; ++w) {
            tot[w] = (sc[w] + pp[s * 8 + w]) * 0.125f + pbr[w];
            mx = fmaxf(mx, tot[w]);
        }
        float sum = 0.f;
#pragma unroll
        for (int w = 0; w < 7; ++w) {
            tot[w] = __expf(tot[w] - mx);
            sum += tot[w];
        }
        const float inv = 1.f / sum;
#pragma unroll
        for (int w = 0; w < 7; ++w) pp[s * 8 + w] = tot[w] * inv;
    }
    __syncthreads();

    float p[7];
#pragma unroll
    for (int w = 0; w < 7; ++w) p[w] = pp[s * 8 + w];

    const uint4* varr = (const uint4*)&lds[VO];
    uint4 ov[4];
#pragma unroll
    for (int c = 0; c < 4; ++c) {
        float o[8] = {0.f, 0.f, 0.f, 0.f, 0.f, 0.f, 0.f, 0.f};
#pragma unroll
        for (int w = 0; w < 7; ++w) {
            int hrow = s + w;
            uint4 vc = varr[hrow * 8 + ((cbase + c) ^ (hrow & 7))];
            float vf[8];
            unpack8(vc, vf);
#pragma unroll
            for (int j = 0; j < 8; ++j) o[j] += p[w] * vf[j];
        }
        ov[c].x = pack2(o[0], o[1]);
        ov[c].y = pack2(o[2], o[3]);
        ov[c].z = pack2(o[4], o[5]);
        ov[c].w = pack2(o[6], o[7]);
    }
    uint16_t* orow = attn + ((size_t)(bn * 256 + s)) * 512 + h * 64 + cbase * 8;
#pragma unroll
    for (int c = 0; c < 4; ++c) *(uint4*)(orow + c * 8) = ov[c];
#undef STAGE_B
#undef A_GL
#undef PACK_WRITE
#undef READS
#undef BODY
}

// ---------------------------------------------------------------------------
// 256x128-tile bf16 GEMM (round-6 pipeline, swapped-operand MFMA -> C^T
// frags, contiguous dwordx4 stores). Output projection.
// ---------------------------------------------------------------------------
template <bool F32OUT>
__global__ __launch_bounds__(512, 4)
void gemm_mn(const uint16_t* __restrict__ A, const uint16_t* __restrict__ BT,
             void* __restrict__ Cout, int M, int N, int K) {
    __shared__ __align__(16) uint16_t lds[36864];  // 72 KB (3 bufs)

    const int tid  = threadIdx.x;
    const int lane = tid & 63;
    const int wv   = tid >> 6;
    const int r    = lane & 15;
    const int quad = lane >> 4;
    const int wr   = wv >> 1;
    const int wc   = wv & 1;
    const long bm0 = (long)blockIdx.x * 256;
    const long bn0 = (long)blockIdx.y * 128;
    const int NT   = K >> 5;

#define SRC_ROWCOL(d_, row_, col_) do {                                                 \
        int ln_ = (d_) >> 3, pre_ = ((d_) & 7) ^ (ln_ & 7);                             \
        row_ = 2 * ln_ + (pre_ >> 2);                                                   \
        col_ = (pre_ & 3) * 8;                                                          \
    } while (0)
    int rA0, cA0, rA1, cA1, rB0, cB0;
    SRC_ROWCOL(tid,       rA0, cA0);
    SRC_ROWCOL(tid + 512, rA1, cA1);
    SRC_ROWCOL(tid,       rB0, cB0);
    const uint16_t* pA0 = A  + (bm0 + rA0) * (long)K + cA0;
    const uint16_t* pA1 = A  + (bm0 + rA1) * (long)K + cA1;
    const uint16_t* pB0 = BT + (bn0 + rB0) * (long)K + cB0;
#undef SRC_ROWCOL

#define STAGE(b_, t_) do {                                                              \
        GLOAD_LDS16(pA0 + (t_) * 32, &lds[(b_) * 8192 + tid * 8]);                      \
        GLOAD_LDS16(pA1 + (t_) * 32, &lds[(b_) * 8192 + (tid + 512) * 8]);              \
        GLOAD_LDS16(pB0 + (t_) * 32, &lds[24576 + (b_) * 4096 + tid * 8]);              \
    } while (0)

    const int p_ln  = (((r & 1) << 2) | quad) ^ ((r >> 1) & 7);
    const int aLane = wr * 2048 + (r >> 1) * 64 + p_ln * 8;
    const int bLane = 24576 + wc * 2048 + (r >> 1) * 64 + p_ln * 8;

#define DS_A(mf_) ds_read16(&lds[aoff + aLane + (mf_) * 512])
#define DS_B(nf_) ds_read16(&lds[boff + bLane + (nf_) * 512])
#define WAITK2 do { asm volatile("s_waitcnt lgkmcnt(2)" ::: "memory");                  \
                    __builtin_amdgcn_sched_barrier(0); } while (0)
#define WAITK0 do { asm volatile("s_waitcnt lgkmcnt(0)" ::: "memory");                  \
                    __builtin_amdgcn_sched_barrier(0); } while (0)
#define MFMA_CL(m0_, f0_, f1_)                                                          \
    __builtin_amdgcn_s_setprio(1);                                                      \
    _Pragma("unroll")                                                                   \
    for (int nf = 0; nf < 4; ++nf)                                                      \
        acc[(m0_)][nf] = __builtin_amdgcn_mfma_f32_16x16x32_bf16(bfr[nf], f0_,          \
                                                                 acc[(m0_)][nf], 0, 0, 0); \
    _Pragma("unroll")                                                                   \
    for (int nf = 0; nf < 4; ++nf)                                                      \
        acc[(m0_) + 1][nf] = __builtin_amdgcn_mfma_f32_16x16x32_bf16(bfr[nf], f1_,      \
                                                                 acc[(m0_) + 1][nf], 0, 0, 0); \
    __builtin_amdgcn_s_setprio(0);

    f32x4 acc[4][4];
#pragma unroll
    for (int mf = 0; mf < 4; ++mf)
#pragma unroll
        for (int nf = 0; nf < 4; ++nf) acc[mf][nf] = (f32x4){0.f, 0.f, 0.f, 0.f};

    STAGE(0, 0);
    STAGE(1, 1);
    asm volatile("s_waitcnt vmcnt(3)" ::: "memory");
    __builtin_amdgcn_s_barrier();

    int b = 0, bs = 2;
    for (int t = 0; t < NT; ++t) {
        const int aoff = b * 8192;
        const int boff = b * 4096;

        if (t + 2 < NT) STAGE(bs, t + 2);

        bf16x8 bfr[4], a0, a1, a2, a3;
#pragma unroll
        for (int nf = 0; nf < 4; ++nf) bfr[nf] = DS_B(nf);
        a0 = DS_A(0); a1 = DS_A(1);
        a2 = DS_A(2); a3 = DS_A(3);

        WAITK2;
        MFMA_CL(0, a0, a1)
        WAITK0;
        MFMA_CL(2, a2, a3)

        if (t + 1 < NT) {
            if (t + 2 < NT)
                asm volatile("s_waitcnt vmcnt(3)" ::: "memory");
            else
                asm volatile("s_waitcnt vmcnt(0)" ::: "memory");
            __builtin_amdgcn_s_barrier();
        }
        b  = (b  == 2) ? 0 : b + 1;
        bs = (bs == 2) ? 0 : bs + 1;
    }

#pragma unroll
    for (int mf = 0; mf < 4; ++mf) {
        long m = bm0 + wr * 64 + mf * 16 + r;
#pragma unroll
        for (int nf = 0; nf < 4; ++nf) {
            long n0 = bn0 + wc * 64 + nf * 16 + quad * 4;
            if (F32OUT) {
                float4 v = {acc[mf][nf][0], acc[mf][nf][1], acc[mf][nf][2], acc[mf][nf][3]};
                *(float4*)((float*)Cout + m * (long)N + n0) = v;
            } else {
                uint2 w;
                w.x = pack2(acc[mf][nf][0], acc[mf][nf][1]);
                w.y = pack2(acc[mf][nf][2], acc[mf][nf][3]);
                *(uint2*)((uint16_t*)Cout + m * (long)N + n0) = w;
            }
        }
    }
#undef STAGE
#undef DS_A
#undef DS_B
#undef WAITK2
#undef WAITK0
#undef MFMA_CL
}

// ---------------------------------------------------------------------------
extern "C" void kernel_launch(void* const* d_in, const int* in_sizes, int n_in,
                              void* d_out, int out_size, void* d_ws, size_t ws_size,
                              hipStream_t stream) {
    const float* X    = (const float*)d_in[0];  // 32768 x 512 fp32
    const float* pb   = (const float*)d_in[1];  // 8 x 256 x 7 fp32
    const float* Wqkv = (const float*)d_in[2];  // 512 x 1536 fp32
    const float* Wout = (const float*)d_in[3];  // 512 x 512 fp32
    float* out = (float*)d_out;                 // 32768 x 512 fp32

    char* ws = (char*)d_ws;
    uint16_t* WqkvT = (uint16_t*)(ws);                  // 1536x512 bf16 = 1.5 MB
    uint16_t* WoutT = (uint16_t*)(ws + 1572864);        // 512x512  bf16 = 0.5 MB
    uint16_t* attnb = (uint16_t*)(ws + 2097152);        // 32768x512 bf16 = 32 MB

    prep<<<4096, 256, 0, stream>>>(Wqkv, Wout, WqkvT, WoutT);
    gemm_qkv_attn<<<1024, 512, 0, stream>>>(X, WqkvT, pb, attnb);
    gemm_mn<true><<<dim3(128, 4), 512, 0, stream>>>(attnb, WoutT, out, 32768, 512, 512);
}